// Round 9
// baseline (506.139 us; speedup 1.0000x reference)
//
#include <hip/hip_runtime.h>
#include <hip/hip_bf16.h>

// Problem constants (fixed by reference setup_inputs):
//   K3=27, PAIRS_PER_K=131072 (=2^17), N_VOX=262144 (=2^18), C_IN=C_OUT=32
//   M = 3,538,944 pairs. out = [262144][32] fp32.
//
// History: R1 113M fp32 atomics = 5.9ms. R4 MFMA gather 312us. R6/R9:
// scratch spill (WRITE_SIZE explosion = spill signature). R7 split-k 497us.
// R10 397us: 2-slot dense + feat16 -> gather 154. R11 389: probes-then-rows
// -> 138. R12: claim passes are random-line-throughput bound, not MLP.
// R13 362us: packed T64, zero-store winners; gather flat 136 => gather is
// ROW-REQUEST-rate bound; claim ~170.
// R14 375us: bucket scatter + LDS 2-slot binning. Scatter = 150us dominant:
// (a) put_pair was a SERIAL atomic->store chain x4 (~2400cy exposed);
// (b) WRITE 168MB = partial-line evictions (8x4MB slices = one XCD L2 each,
// zero retention). Gather ~flat vs R13 (row-bound, probes were cheap).
// R15 (this): scatter: 4 atomics batched BEFORE 4 stores (R13-passB lesson,
// 4x MLP on atomic path); bucket stores non-temporal (write-once data ->
// don't churn L2, land in L3). Gather: speculative bucket read (masked by
// cnt), early cnt/ecnt issue. Null-result tripwire: scatter flat => atomic-
// THROUGHPUT bound => pivot to 0.67M-atomic claim next.

#define N_VOX    262144
#define LOG2_NV  18
#define C_CH     32
#define K3       27
#define LOG2_PPK 17
#define BLOCK    256
#define ECAP     4096
#define PLPAD    36   // plane row stride: rows differ by 36%32=4 -> 2-way max
#define FRAGN    (K3 * 2 * 64)   // uint4 fragments (hi-precision W only)
#define NF16     (N_VOX * 4)     // feat16 uint4 work items
#define NBUCK    16384           // N_VOX / 16
#define SCAP     64              // entries per bucket slice (8 slices)
#define NSLOT    (K3 * 16)       // 432 LDS slots per block

typedef __attribute__((ext_vector_type(8))) short bf16x8;
typedef __attribute__((ext_vector_type(4))) float f32x4;

__device__ __forceinline__ unsigned short f2bf(float f) {
  union { __hip_bfloat16 h; unsigned short u; } cv;
  cv.h = __float2bfloat16(f);
  return cv.u;
}

// ---------------------------------------------------------------------------
// Setup: clear cnt+ecnt (0.5 MB), build feat16 (bf16 rows) and Bf (W in
// mfma B-operand lane layout, m89/m91).
__global__ __launch_bounds__(BLOCK) void setup_kernel(
    int4* __restrict__ clrC, long nc4,
    const float* __restrict__ in_feature, unsigned short* __restrict__ feat16,
    int use16, const float* __restrict__ kernel_w,
    unsigned short* __restrict__ Bf) {
  long idx = (long)blockIdx.x * BLOCK + threadIdx.x;
  if (idx < nc4) {
    clrC[idx] = make_int4(0, 0, 0, 0);
    return;
  }
  idx -= nc4;
  if (use16) {
    if (idx < NF16) {
      const float4* src = (const float4*)in_feature + (idx << 1);
      float4 f0 = src[0], f1 = src[1];
      union { unsigned short u[8]; uint4 v; } pk;
      pk.u[0] = f2bf(f0.x); pk.u[1] = f2bf(f0.y);
      pk.u[2] = f2bf(f0.z); pk.u[3] = f2bf(f0.w);
      pk.u[4] = f2bf(f1.x); pk.u[5] = f2bf(f1.y);
      pk.u[6] = f2bf(f1.z); pk.u[7] = f2bf(f1.w);
      ((uint4*)feat16)[idx] = pk.v;
      return;
    }
    idx -= NF16;
  }
  if (idx < FRAGN) {
    int wid = (int)idx;
    int lane = wid & 63;
    int kc = wid >> 6;
    int k = kc >> 1, t = kc & 1;
    int i0 = (lane >> 4) * 8;
    int c = t * 16 + (lane & 15);
    union { unsigned short u[8]; uint4 v; } pk;
#pragma unroll
    for (int j = 0; j < 8; ++j)
      pk.u[j] = f2bf(kernel_w[(k << 10) + (i0 + j) * C_CH + c]);
    ((uint4*)Bf)[wid] = pk.v;
  }
}

// ---------------------------------------------------------------------------
// Scatter: one pass. Pair (vox,in,k) -> bucket[slice][vox>>4][pos], entry =
// k[26:22] | v4[21:18] | in[17:0]. slice = blockIdx&7. ALL FOUR atomics
// issue before any store (4x MLP on the atomic path); bucket stores are
// non-temporal (write-once, read next kernel -> L3, don't churn L2).
__global__ __launch_bounds__(BLOCK) void scatter_pairs(
    const int4* __restrict__ nbmap2, int* __restrict__ cnt,
    int* __restrict__ bucket, int* __restrict__ ecnt,
    int2* __restrict__ elist, int Mq) {
  int q = blockIdx.x * BLOCK + threadIdx.x;
  if (q >= Mq) return;
  int slice = blockIdx.x & 7;
  int4 na = nbmap2[q * 2];
  int4 nb = nbmap2[q * 2 + 1];
  int p0 = q << 2;
  int k0 = (p0 | 0) >> LOG2_PPK, k1 = (p0 | 1) >> LOG2_PPK;
  int k2 = (p0 | 2) >> LOG2_PPK, k3 = (p0 | 3) >> LOG2_PPK;
  int sb0 = slice * NBUCK + (na.y >> 4);
  int sb1 = slice * NBUCK + (na.w >> 4);
  int sb2 = slice * NBUCK + (nb.y >> 4);
  int sb3 = slice * NBUCK + (nb.w >> 4);
  int pos0 = atomicAdd(&cnt[sb0], 1);         // all four in flight
  int pos1 = atomicAdd(&cnt[sb1], 1);
  int pos2 = atomicAdd(&cnt[sb2], 1);
  int pos3 = atomicAdd(&cnt[sb3], 1);
  int e0 = (k0 << 22) | ((na.y & 15) << 18) | na.x;
  int e1 = (k1 << 22) | ((na.w & 15) << 18) | na.z;
  int e2 = (k2 << 22) | ((nb.y & 15) << 18) | nb.x;
  int e3 = (k3 << 22) | ((nb.w & 15) << 18) | nb.z;
  if (pos0 < SCAP)
    __builtin_nontemporal_store(e0, &bucket[(long)sb0 * SCAP + pos0]);
  if (pos1 < SCAP)
    __builtin_nontemporal_store(e1, &bucket[(long)sb1 * SCAP + pos1]);
  if (pos2 < SCAP)
    __builtin_nontemporal_store(e2, &bucket[(long)sb2 * SCAP + pos2]);
  if (pos3 < SCAP)
    __builtin_nontemporal_store(e3, &bucket[(long)sb3 * SCAP + pos3]);
  if (pos0 >= SCAP) {
    int ep = atomicAdd(ecnt, 1);
    if (ep < ECAP) elist[ep] = make_int2(na.y, (k0 << LOG2_NV) | na.x);
  }
  if (pos1 >= SCAP) {
    int ep = atomicAdd(ecnt, 1);
    if (ep < ECAP) elist[ep] = make_int2(na.w, (k1 << LOG2_NV) | na.z);
  }
  if (pos2 >= SCAP) {
    int ep = atomicAdd(ecnt, 1);
    if (ep < ECAP) elist[ep] = make_int2(nb.y, (k2 << LOG2_NV) | nb.x);
  }
  if (pos3 >= SCAP) {
    int ep = atomicAdd(ecnt, 1);
    if (ep < ECAP) elist[ep] = make_int2(nb.w, (k3 << LOG2_NV) | nb.z);
  }
}

// ---------------------------------------------------------------------------
// Gather: block = 1 bucket = 16 voxels, 4 waves x 7 k each. Phase 1: read
// bucket slices (speculative first row, masked by cnt) + elist leftovers,
// 2-slot claim in LDS; 3rd+ -> flatE fp32 path. Phase 2 (proven body):
// rows from feat16 for both slots, 28 MFMA, plane dump, serial fp32
// overflow loop (dist-1 prefetch), 4-plane merge + bias.
template <int F16>
__global__ __launch_bounds__(BLOCK, 4) void gather_csr_kernel(
    const float* __restrict__ in_feature,
    const unsigned short* __restrict__ feat16,
    const float* __restrict__ kernel_w,
    const float* __restrict__ bias,
    const int* __restrict__ cnt,
    const int* __restrict__ bucket,
    const int* __restrict__ ecnt,
    const int2* __restrict__ elist,
    const unsigned short* __restrict__ Bf,
    float* __restrict__ out) {
  __shared__ float plane[4][16][PLPAD];       // 9216 B: per-wave partials
  __shared__ int flatE[320];                  // fp32-path entries
  __shared__ int ls1[NSLOT], ls2[NSLOT];      // slot 1/2 in-indices (-1 empty)
  __shared__ int lcnt[NSLOT];
  __shared__ int scn[8];
  __shared__ int extraN;

  const int tid = threadIdx.x;
  const int w = tid >> 6;
  const int lane = tid & 63;
  const int r16 = lane & 15;
  const int quad = lane >> 4;
  const int b = blockIdx.x;
  const int vb = b << 4;

  // ---- early issue: cnt, ecnt, speculative first bucket row ----
  int scn_r = 0;
  if (tid < 8) scn_r = cnt[tid * NBUCK + b];
  int ne = *ecnt;                             // uniform broadcast load
  const int s = tid >> 5;                     // slice 0..7, 32 threads each
  const int i0 = tid & 31;
  const int* base = bucket + (long)(s * NBUCK + b) * SCAP;
  int e_spec = base[i0];                      // speculative (i0 < SCAP)

  for (int i = tid; i < NSLOT; i += BLOCK) {
    ls1[i] = -1; ls2[i] = -1; lcnt[i] = 0;
  }
  if (tid < 8) scn[tid] = scn_r < SCAP ? scn_r : SCAP;
  if (tid == 0) extraN = 0;
  __syncthreads();

  // ---- bin bucket entries into LDS slots ----
  {
    const int n = scn[s];
    for (int i = i0; i < n; i += 32) {
      int e = (i == i0) ? e_spec : base[i];
      int sl = (e >> 18) & 511;               // k*16 + v4
      int in = e & 0x3FFFF;
      int pos = atomicAdd(&lcnt[sl], 1);
      if (pos == 0) ls1[sl] = in;
      else if (pos == 1) ls2[sl] = in;
      else {
        int x = atomicAdd(&extraN, 1);
        if (x < 320)
          flatE[x] = (((e >> 18) & 15) << 24) | (((e >> 22) & 31) << 18) | in;
      }
    }
  }
  // ---- elist leftovers (global safety net, ~tens of entries) ----
  if (tid < 64) {
    if (ne > ECAP) ne = ECAP;
    for (int e2 = tid; e2 < ne; e2 += 64) {
      int2 ent = elist[e2];
      unsigned dv = (unsigned)(ent.x - vb);
      if (dv < 16u) {
        int x = atomicAdd(&extraN, 1);
        if (x < 320) flatE[x] = (dv << 24) | ent.y;
      }
    }
  }
  __syncthreads();
  int tot = extraN;
  if (tot > 320) tot = 320;

  // ---- dense rows for both slots (probe = LDS read, no global trip) ----
  const int kb = w * 7;
  const int kn = (w == 3) ? 6 : 7;
  bf16x8 R0[7], R1[7];
#pragma unroll
  for (int d = 0; d < 7; ++d) {
    int t = (d < kn) ? ls1[(kb + d) * 16 + r16] : -1;
    int in = (t >= 0) ? t : 0;
    bf16x8 a;
    if (F16) {
      a = *reinterpret_cast<const bf16x8*>(feat16 + (in << 5) + (quad << 3));
    } else {
      const float4* ap = (const float4*)(in_feature + (in << 5) + (quad << 3));
      float4 f0 = ap[0], f1 = ap[1];
      a[0] = (short)f2bf(f0.x); a[1] = (short)f2bf(f0.y);
      a[2] = (short)f2bf(f0.z); a[3] = (short)f2bf(f0.w);
      a[4] = (short)f2bf(f1.x); a[5] = (short)f2bf(f1.y);
      a[6] = (short)f2bf(f1.z); a[7] = (short)f2bf(f1.w);
    }
    if (t < 0) a = (bf16x8)0;
    R0[d] = a;
  }
#pragma unroll
  for (int d = 0; d < 7; ++d) {
    int t = (d < kn) ? ls2[(kb + d) * 16 + r16] : -1;
    int in = (t >= 0) ? t : 0;
    bf16x8 a;
    if (F16) {
      a = *reinterpret_cast<const bf16x8*>(feat16 + (in << 5) + (quad << 3));
    } else {
      const float4* ap = (const float4*)(in_feature + (in << 5) + (quad << 3));
      float4 f0 = ap[0], f1 = ap[1];
      a[0] = (short)f2bf(f0.x); a[1] = (short)f2bf(f0.y);
      a[2] = (short)f2bf(f0.z); a[3] = (short)f2bf(f0.w);
      a[4] = (short)f2bf(f1.x); a[5] = (short)f2bf(f1.y);
      a[6] = (short)f2bf(f1.z); a[7] = (short)f2bf(f1.w);
    }
    if (t < 0) a = (bf16x8)0;
    R1[d] = a;
  }

  // ---- MFMA sweeps (hi-precision W only) ----
  f32x4 acc0 = {0.f, 0.f, 0.f, 0.f};
  f32x4 acc1 = {0.f, 0.f, 0.f, 0.f};
  const uint4* bfp = (const uint4*)Bf;
#pragma unroll
  for (int d = 0; d < 7; ++d) {
    if (d < kn) {
      int k = kb + d;
      uint4 h0 = bfp[(k * 2 + 0) * 64 + lane];
      uint4 h1 = bfp[(k * 2 + 1) * 64 + lane];
      acc0 = __builtin_amdgcn_mfma_f32_16x16x32_bf16(
          R0[d], *reinterpret_cast<const bf16x8*>(&h0), acc0, 0, 0, 0);
      acc1 = __builtin_amdgcn_mfma_f32_16x16x32_bf16(
          R0[d], *reinterpret_cast<const bf16x8*>(&h1), acc1, 0, 0, 0);
    }
  }
#pragma unroll
  for (int d = 0; d < 7; ++d) {
    if (d < kn) {
      int k = kb + d;
      uint4 h0 = bfp[(k * 2 + 0) * 64 + lane];
      uint4 h1 = bfp[(k * 2 + 1) * 64 + lane];
      acc0 = __builtin_amdgcn_mfma_f32_16x16x32_bf16(
          R1[d], *reinterpret_cast<const bf16x8*>(&h0), acc0, 0, 0, 0);
      acc1 = __builtin_amdgcn_mfma_f32_16x16x32_bf16(
          R1[d], *reinterpret_cast<const bf16x8*>(&h1), acc1, 0, 0, 0);
    }
  }

  // ---- dump partials (C/D: col=lane&15, row=quad*4+reg — m89/m91) ----
#pragma unroll
  for (int reg = 0; reg < 4; ++reg) {
    int row = quad * 4 + reg;
    plane[w][row][r16] = acc0[reg];
    plane[w][row][16 + r16] = acc1[reg];
  }

  // ---- residual overflow: entries i = w, w+4, ... ; dist-1 prefetch ----
  const int c32 = lane & 31, h = lane >> 5;
  int i = w;
  int e_cur = 0;
  float4 p0, p1, p2, p3;
  if (i < tot) {
    e_cur = flatE[i];
    const float4* ar =
        (const float4*)(in_feature + ((e_cur & 0x3FFFF) << 5) + (h << 4));
    p0 = ar[0]; p1 = ar[1]; p2 = ar[2]; p3 = ar[3];
  }
  while (i < tot) {
    const int e = e_cur;
    float4 q0 = p0, q1 = p1, q2 = p2, q3 = p3;
    const int inext = i + 4;
    if (inext < tot) {
      e_cur = flatE[inext];
      const float4* ar =
          (const float4*)(in_feature + ((e_cur & 0x3FFFF) << 5) + (h << 4));
      p0 = ar[0]; p1 = ar[1]; p2 = ar[2]; p3 = ar[3];
    }
    const int k2 = (e >> LOG2_NV) & 31;
    const int rr = (e >> 24) & 15;
    const float* wcol = kernel_w + (k2 << 10) + (h << 4) * C_CH + c32;
    float psum = 0.f;
    psum = fmaf(q0.x, wcol[0 * C_CH], psum);
    psum = fmaf(q0.y, wcol[1 * C_CH], psum);
    psum = fmaf(q0.z, wcol[2 * C_CH], psum);
    psum = fmaf(q0.w, wcol[3 * C_CH], psum);
    psum = fmaf(q1.x, wcol[4 * C_CH], psum);
    psum = fmaf(q1.y, wcol[5 * C_CH], psum);
    psum = fmaf(q1.z, wcol[6 * C_CH], psum);
    psum = fmaf(q1.w, wcol[7 * C_CH], psum);
    psum = fmaf(q2.x, wcol[8 * C_CH], psum);
    psum = fmaf(q2.y, wcol[9 * C_CH], psum);
    psum = fmaf(q2.z, wcol[10 * C_CH], psum);
    psum = fmaf(q2.w, wcol[11 * C_CH], psum);
    psum = fmaf(q3.x, wcol[12 * C_CH], psum);
    psum = fmaf(q3.y, wcol[13 * C_CH], psum);
    psum = fmaf(q3.z, wcol[14 * C_CH], psum);
    psum = fmaf(q3.w, wcol[15 * C_CH], psum);
    psum += __shfl_xor(psum, 32);
    if (h == 0) plane[w][rr][c32] += psum;    // own plane: no cross-wave race
    i = inext;
  }

  // ---- merge 4 planes + bias, one float2 store per thread ----
  __syncthreads();
  const int mr = tid >> 4;
  const int mc = (tid & 15) << 1;
  float s0 = plane[0][mr][mc] + plane[1][mr][mc] + plane[2][mr][mc] +
             plane[3][mr][mc] + bias[mc];
  float s1 = plane[0][mr][mc + 1] + plane[1][mr][mc + 1] +
             plane[2][mr][mc + 1] + plane[3][mr][mc + 1] + bias[mc + 1];
  float2 o; o.x = s0; o.y = s1;
  *(float2*)(out + ((vb + mr) << 5) + mc) = o;
}

// ---------------------------------------------------------------------------
// Fallback (tiny ws): round-1 direct-atomic version. Correct, slow.
__global__ __launch_bounds__(BLOCK) void init_bias_kernel(
    float* __restrict__ out, const float* __restrict__ bias, int n4) {
  int idx = blockIdx.x * blockDim.x + threadIdx.x;
  if (idx >= n4) return;
  ((float4*)out)[idx] = ((const float4*)bias)[idx & 7];
}

__global__ __launch_bounds__(BLOCK) void scatter_conv_kernel(
    const float* __restrict__ in_feature, const float* __restrict__ kernel_w,
    const int* __restrict__ nbmap, float* __restrict__ out) {
  const int k = blockIdx.x >> 9;
  const int pair = blockIdx.x * BLOCK + threadIdx.x;
  const float* __restrict__ Wk = kernel_w + k * (C_CH * C_CH);
  const int2 nb = ((const int2*)nbmap)[pair];
  const float4* __restrict__ inrow =
      (const float4*)(in_feature + (long)nb.x * C_CH);
  float a[C_CH];
#pragma unroll
  for (int j = 0; j < 8; ++j) ((float4*)a)[j] = inrow[j];
  float acc[C_CH];
#pragma unroll
  for (int c = 0; c < C_CH; ++c) acc[c] = 0.0f;
#pragma unroll
  for (int i = 0; i < C_CH; ++i) {
    const float av = a[i];
#pragma unroll
    for (int c = 0; c < C_CH; ++c)
      acc[c] = fmaf(av, Wk[i * C_CH + c], acc[c]);
  }
  float* __restrict__ orow = out + (long)nb.y * C_CH;
#pragma unroll
  for (int c = 0; c < C_CH; ++c) atomicAdd(orow + c, acc[c]);
}

// ===========================================================================
extern "C" void kernel_launch(void* const* d_in, const int* in_sizes, int n_in,
                              void* d_out, int out_size, void* d_ws,
                              size_t ws_size, hipStream_t stream) {
  const float* in_feature = (const float*)d_in[0];
  const float* kernel_w   = (const float*)d_in[1];
  const float* bias       = (const float*)d_in[2];
  const int*   nbmap      = (const int*)d_in[3];
  float* out = (float*)d_out;
  const int M = in_sizes[3] / 2;                 // 3,538,944
  const int Mq = M / 4;                          // quads of pairs (exact)

  // ws (ints): cnt[8*NBUCK] | ecnt[64] | elist[2*ECAP] | Bf[13824]
  //            | bucket[8*NBUCK*SCAP] | feat16[N_VOX*16 if use16]
  const long CNT_I   = 8L * NBUCK;                  // 131072
  const long HDR_I   = CNT_I + 64 + 2 * ECAP + 13824;
  const long BUCK_I  = 8L * NBUCK * SCAP;           // 8,388,608 (32 MB)
  const long F16_I   = (long)N_VOX * 16;            // 4,194,304 (16 MB)
  long ws_ints = (long)(ws_size / 4);
  int use16 = 0, csr = 0;
  if (ws_ints >= HDR_I + BUCK_I + F16_I) { csr = 1; use16 = 1; }
  else if (ws_ints >= HDR_I + BUCK_I)    { csr = 1; }

  if (!csr) {                                    // tiny ws: direct atomics
    const int n4 = out_size / 4;
    init_bias_kernel<<<(n4 + BLOCK - 1) / BLOCK, BLOCK, 0, stream>>>(out, bias,
                                                                     n4);
    scatter_conv_kernel<<<M / BLOCK, BLOCK, 0, stream>>>(in_feature, kernel_w,
                                                         nbmap, out);
    return;
  }

  int* cnt      = (int*)d_ws;                       // [8][NBUCK]
  int* ecnt     = cnt + CNT_I;                      // [64] (use [0])
  int2* elist   = (int2*)(ecnt + 64);               // [ECAP]
  unsigned short* Bf = (unsigned short*)(ecnt + 64 + 2 * ECAP);  // [27648]
  int* bucket   = ((int*)Bf) + 13824;               // [8][NBUCK][SCAP]
  unsigned short* feat16 = (unsigned short*)(bucket + BUCK_I);

  // Setup: clear cnt+ecnt (contiguous) + feat16 + Bf.
  const long nc4 = (CNT_I + 64) / 4;
  const long total = nc4 + (use16 ? (long)NF16 : 0) + FRAGN;
  const long sblocks = (total + BLOCK - 1) / BLOCK;
  setup_kernel<<<(int)sblocks, BLOCK, 0, stream>>>(
      (int4*)cnt, nc4, in_feature, feat16, use16, kernel_w, Bf);

  scatter_pairs<<<(Mq + BLOCK - 1) / BLOCK, BLOCK, 0, stream>>>(
      (const int4*)nbmap, cnt, bucket, ecnt, elist, Mq);

  if (use16)
    gather_csr_kernel<1><<<NBUCK, BLOCK, 0, stream>>>(
        in_feature, feat16, kernel_w, bias, cnt, bucket, ecnt, elist, Bf, out);
  else
    gather_csr_kernel<0><<<NBUCK, BLOCK, 0, stream>>>(
        in_feature, feat16, kernel_w, bias, cnt, bucket, ecnt, elist, Bf, out);
}

// Round 10
// 362.448 us; speedup vs baseline: 1.3964x; 1.3964x over previous
//
#include <hip/hip_runtime.h>
#include <hip/hip_bf16.h>

// Problem constants (fixed by reference setup_inputs):
//   K3=27, PAIRS_PER_K=131072 (=2^17), N_VOX=262144 (=2^18), C_IN=C_OUT=32
//   M = 3,538,944 pairs. out = [262144][32] fp32.
//
// History: R1 113M fp32 atomics = 5.9ms. R4 MFMA gather 312us. R6/R9:
// scratch spill (WRITE_SIZE explosion = spill signature). R7 split-k 497us.
// R10 397us: 2-slot dense + feat16 -> gather 154. R11 389: probes-then-rows
// -> 138. R12: claim passes are random-line-throughput bound, not MLP.
// R13 362us BEST: packed T64 word p|in1|in2 (8B plain-store claim,
// zero-store winners, ONE probe round feeds both MFMA rounds); gather 136
// (FETCH 219MB = one 64B row per contribution = minimal), claim ~170 at
// random-line RFO+WB floor. R14 375us: bucket scatter+LDS binning — scatter
// 150us (atomic+RFO bound), no gather gain. R15 506us: nontemporal bucket
// stores DISASTER (253MB partial-line writebacks; NT defeats L2 write-
// combining on scattered small stores). Bucket architecture falsified.
// R16 (this): REVERT to R13 verbatim — best measured configuration.

#define N_VOX    262144
#define LOG2_NV  18
#define C_CH     32
#define K3       27
#define LOG2_PPK 17
#define BLOCK    256
#define FLAG_FIN 0x40000000
#define ECAP     4096
#define PLPAD    36   // plane row stride: rows differ by 36%32=4 -> 2-way max
#define FRAGN    (K3 * 2 * 64)   // uint4 fragments (hi-precision W only)
#define NF16     (N_VOX * 4)     // feat16 uint4 work items

typedef __attribute__((ext_vector_type(8))) short bf16x8;
typedef __attribute__((ext_vector_type(4))) float f32x4;
typedef unsigned long long ull;

#define PMASK   0x3FFFFFull            // p field [21:0]
#define EMPTY2(w) (((w) >> 58) == 0x3Full)

__device__ __forceinline__ unsigned short f2bf(float f) {
  union { __hip_bfloat16 h; unsigned short u; } cv;
  cv.h = __float2bfloat16(f);
  return cv.u;
}

// ---------------------------------------------------------------------------
// Setup: one kernel does all init. Work-id ranges (disjoint memory):
//   [0, nt4)            : clear T/T64 to -1, int4 stores
//   [nt4, nt4+nc4)      : clear ovf_cnt + ecnt to 0
//   [.., +NF16 if use16): feat16 = bf16(in_feature), uint4 stores
//   [.., +FRAGN)        : Bf = W permuted to mfma B-operand lanes (m89/m91)
__global__ __launch_bounds__(BLOCK) void setup_kernel(
    int4* __restrict__ clrT, long nt4, int4* __restrict__ clrC, long nc4,
    const float* __restrict__ in_feature, unsigned short* __restrict__ feat16,
    int use16, const float* __restrict__ kernel_w,
    unsigned short* __restrict__ Bf) {
  long idx = (long)blockIdx.x * BLOCK + threadIdx.x;
  if (idx < nt4) {
    clrT[idx] = make_int4(-1, -1, -1, -1);
    return;
  }
  idx -= nt4;
  if (idx < nc4) {
    clrC[idx] = make_int4(0, 0, 0, 0);
    return;
  }
  idx -= nc4;
  if (use16) {
    if (idx < NF16) {
      const float4* src = (const float4*)in_feature + (idx << 1);
      float4 f0 = src[0], f1 = src[1];
      union { unsigned short u[8]; uint4 v; } pk;
      pk.u[0] = f2bf(f0.x); pk.u[1] = f2bf(f0.y);
      pk.u[2] = f2bf(f0.z); pk.u[3] = f2bf(f0.w);
      pk.u[4] = f2bf(f1.x); pk.u[5] = f2bf(f1.y);
      pk.u[6] = f2bf(f1.z); pk.u[7] = f2bf(f1.w);
      ((uint4*)feat16)[idx] = pk.v;
      return;
    }
    idx -= NF16;
  }
  if (idx < FRAGN) {
    int wid = (int)idx;
    int lane = wid & 63;
    int kc = wid >> 6;
    int k = kc >> 1, t = kc & 1;
    int i0 = (lane >> 4) * 8;
    int c = t * 16 + (lane & 15);
    union { unsigned short u[8]; uint4 v; } pk;
#pragma unroll
    for (int j = 0; j < 8; ++j)
      pk.u[j] = f2bf(kernel_w[(k << 10) + (i0 + j) * C_CH + c]);
    ((uint4*)Bf)[wid] = pk.v;
  }
}

// ---------------------------------------------------------------------------
// PACKED pass A: last-writer-wins claim, one plain 8B store per pair
// (word = p | in<<22 | empty2 marker). 4 pairs/thread.
__global__ __launch_bounds__(BLOCK) void passA_packed(
    const int4* __restrict__ nbmap2, ull* __restrict__ T64, int Mq) {
  int q = blockIdx.x * BLOCK + threadIdx.x;
  if (q >= Mq) return;
  int4 na = nbmap2[q * 2];
  int4 nb = nbmap2[q * 2 + 1];
  int p0 = q << 2, p1 = p0 | 1, p2 = p0 | 2, p3 = p0 | 3;
  const ull EM = 0x3Full << 58;
  T64[((long)(p0 >> LOG2_PPK) << LOG2_NV) + na.y] =
      (ull)p0 | ((ull)na.x << 22) | EM;
  T64[((long)(p1 >> LOG2_PPK) << LOG2_NV) + na.w] =
      (ull)p1 | ((ull)na.z << 22) | EM;
  T64[((long)(p2 >> LOG2_PPK) << LOG2_NV) + nb.y] =
      (ull)p2 | ((ull)nb.x << 22) | EM;
  T64[((long)(p3 >> LOG2_PPK) << LOG2_NV) + nb.w] =
      (ull)p3 | ((ull)nb.z << 22) | EM;
}

// Overflow append (shared by packed/legacy loser paths).
__device__ __forceinline__ void ovf_push(
    int vox, int k, int in, int* __restrict__ ovf_cnt, int* __restrict__ ovf,
    int S2, int* __restrict__ ecnt, int2* __restrict__ elist) {
  int pos = atomicAdd(&ovf_cnt[vox], 1);
  if (pos < S2) {
    ovf[(pos << LOG2_NV) + vox] = (k << LOG2_NV) | in;
  } else {
    int ep = atomicAdd(ecnt, 1);
    if (ep < ECAP) elist[ep] = make_int2(vox, (k << LOG2_NV) | in);
  }
}

// PACKED pass B: winner = p-field match -> NOTHING (zero stores). Loser
// CASes the in2 field (preserves [39:0]); occupied -> ovf. 4 pairs/thread,
// all 4 reads issued before any resolution.
__device__ __forceinline__ void resolve_packed(
    int p, int vox, int in, ull w, ull* __restrict__ T64, long idx,
    int* __restrict__ ovf_cnt, int* __restrict__ ovf, int S2,
    int* __restrict__ ecnt, int2* __restrict__ elist) {
  if ((w & PMASK) == (ull)p) return;          // winner: already in slot 1
  ull cur = w;
  for (;;) {
    if (!EMPTY2(cur)) break;                  // slot 2 taken -> ovf
    ull nw = (cur & ((1ull << 40) - 1)) | ((ull)in << 40);
    ull old = atomicCAS(&T64[idx], cur, nw);
    if (old == cur) return;                   // claimed slot 2
    cur = old;
  }
  ovf_push(vox, p >> LOG2_PPK, in, ovf_cnt, ovf, S2, ecnt, elist);
}

__global__ __launch_bounds__(BLOCK) void passB_packed(
    const int4* __restrict__ nbmap2, ull* __restrict__ T64,
    int* __restrict__ ovf_cnt, int* __restrict__ ovf, int S2,
    int* __restrict__ ecnt, int2* __restrict__ elist, int Mq) {
  int q = blockIdx.x * BLOCK + threadIdx.x;
  if (q >= Mq) return;
  int4 na = nbmap2[q * 2];
  int4 nb = nbmap2[q * 2 + 1];
  int p0 = q << 2, p1 = p0 | 1, p2 = p0 | 2, p3 = p0 | 3;
  long i0 = ((long)(p0 >> LOG2_PPK) << LOG2_NV) + na.y;
  long i1 = ((long)(p1 >> LOG2_PPK) << LOG2_NV) + na.w;
  long i2 = ((long)(p2 >> LOG2_PPK) << LOG2_NV) + nb.y;
  long i3 = ((long)(p3 >> LOG2_PPK) << LOG2_NV) + nb.w;
  ull w0 = T64[i0];                           // all four loads in flight
  ull w1 = T64[i1];
  ull w2 = T64[i2];
  ull w3 = T64[i3];
  resolve_packed(p0, na.y, na.x, w0, T64, i0, ovf_cnt, ovf, S2, ecnt, elist);
  resolve_packed(p1, na.w, na.z, w1, T64, i1, ovf_cnt, ovf, S2, ecnt, elist);
  resolve_packed(p2, nb.y, nb.x, w2, T64, i2, ovf_cnt, ovf, S2, ecnt, elist);
  resolve_packed(p3, nb.w, nb.z, w3, T64, i3, ovf_cnt, ovf, S2, ecnt, elist);
}

// ---------------------------------------------------------------------------
// LEGACY (small-ws insurance): single 4B table, FLAG finalize, no slot 2.
__global__ __launch_bounds__(BLOCK) void passA_legacy(
    const int2* __restrict__ nbmap, int* __restrict__ T, int M) {
  int p = blockIdx.x * BLOCK + threadIdx.x;
  if (p >= M) return;
  int2 nb = nbmap[p];
  T[((p >> LOG2_PPK) << LOG2_NV) + nb.y] = p;
}

__global__ __launch_bounds__(BLOCK) void passB_legacy(
    const int2* __restrict__ nbmap, int* __restrict__ T,
    int* __restrict__ ovf_cnt, int* __restrict__ ovf, int S2,
    int* __restrict__ ecnt, int2* __restrict__ elist, int M) {
  int p = blockIdx.x * BLOCK + threadIdx.x;
  if (p >= M) return;
  int2 nb = nbmap[p];
  int idx = ((p >> LOG2_PPK) << LOG2_NV) + nb.y;
  if (T[idx] == p) {
    T[idx] = FLAG_FIN | nb.x;
  } else {
    ovf_push(nb.y, p >> LOG2_PPK, nb.x, ovf_cnt, ovf, S2, ecnt, elist);
  }
}

// ---------------------------------------------------------------------------
// Split-k MFMA gather: block = 4 waves x 16 voxels (same 16 for all waves).
// Wave w owns k in [7w, 7w+kn). PACKED: ONE probe round (8B word) yields
// both rounds' in-indices; then 14 rows (1 trip) + both MFMA sweeps.
// Residual overflow (~7/block) on the fp32 serial path, dist-1 prefetch.
template <int PACKED, int F16>
__global__ __launch_bounds__(BLOCK, 4) void gather_splitk_kernel(
    const float* __restrict__ in_feature,
    const unsigned short* __restrict__ feat16,
    const float* __restrict__ kernel_w,
    const float* __restrict__ bias,
    const void* __restrict__ Tv,
    const int* __restrict__ ovf_cnt,
    const int* __restrict__ ovf,
    const unsigned short* __restrict__ Bf,
    float* __restrict__ out, int S2) {
  __shared__ float plane[4][16][PLPAD];       // 9216 B: per-wave partials
  __shared__ int flatE[256];                  // block's overflow entries
  __shared__ int scnt[16];

  const int tid = threadIdx.x;
  const int w = tid >> 6;
  const int lane = tid & 63;
  const int r16 = lane & 15;
  const int quad = lane >> 4;
  const int vb = blockIdx.x << 4;

  // ---- early issue: counts, speculative ovf entries, probes ----
  const int er = tid & 15;                    // (er, ej): voxel, list pos
  const int ej = tid >> 4;
  int eval = 0;
  if (ej < S2)                                // speculative; masked by scnt
    eval = ovf[(ej << LOG2_NV) + vb + er];
  if (tid < 16) {
    int c = ovf_cnt[vb + tid];
    scnt[tid] = c < S2 ? c : S2;
  }
  const int kb = w * 7;
  const int kn = (w == 3) ? 6 : 7;
  const int v = vb + r16;

  ull wv[7];
  if (PACKED) {
    const ull* T64 = (const ull*)Tv;
#pragma unroll
    for (int d = 0; d < 7; ++d)
      wv[d] = (d < kn) ? T64[((long)(kb + d) << LOG2_NV) + v] : ~0ull;
  } else {
    const int* T = (const int*)Tv;
#pragma unroll
    for (int d = 0; d < 7; ++d) {
      int t = (d < kn) ? T[((kb + d) << LOG2_NV) + v] : -1;
      // legacy: t = FLAG|in (valid) or -1; map to packed-like: in1 field
      wv[d] = (t >= 0) ? (((ull)(t & 0x3FFFF) << 22) | (0x3Full << 58))
                       : ~0ull;
    }
  }
  __syncthreads();                            // scnt visible

  // ---- overflow staging: scalar prefix (no priv arrays), flatE write ----
  int myb = 0, tot = 0;
#pragma unroll
  for (int q = 0; q < 16; ++q) {
    int cq = scnt[q];
    if (q < er) myb += cq;
    tot += cq;
  }
  if (ej < scnt[er])
    flatE[myb + ej] = (er << 24) | eval;
  __syncthreads();                            // flatE ready

  // ---- rows for both rounds (one trip; invalid -> row0 + zero mask) ----
  bf16x8 R0[7], R1[7];
#pragma unroll
  for (int d = 0; d < 7; ++d) {
    bool val1 = (wv[d] & PMASK) != PMASK;
    int in = val1 ? (int)((wv[d] >> 22) & 0x3FFFF) : 0;
    bf16x8 a;
    if (F16) {
      a = *reinterpret_cast<const bf16x8*>(feat16 + (in << 5) + (quad << 3));
    } else {
      const float4* ap = (const float4*)(in_feature + (in << 5) + (quad << 3));
      float4 f0 = ap[0], f1 = ap[1];
      a[0] = (short)f2bf(f0.x); a[1] = (short)f2bf(f0.y);
      a[2] = (short)f2bf(f0.z); a[3] = (short)f2bf(f0.w);
      a[4] = (short)f2bf(f1.x); a[5] = (short)f2bf(f1.y);
      a[6] = (short)f2bf(f1.z); a[7] = (short)f2bf(f1.w);
    }
    if (!val1) a = (bf16x8)0;
    R0[d] = a;
  }
  if (PACKED) {
#pragma unroll
    for (int d = 0; d < 7; ++d) {
      bool val2 = !EMPTY2(wv[d]);
      int in = val2 ? (int)((wv[d] >> 40) & 0x3FFFF) : 0;
      bf16x8 a;
      if (F16) {
        a = *reinterpret_cast<const bf16x8*>(feat16 + (in << 5) + (quad << 3));
      } else {
        const float4* ap =
            (const float4*)(in_feature + (in << 5) + (quad << 3));
        float4 f0 = ap[0], f1 = ap[1];
        a[0] = (short)f2bf(f0.x); a[1] = (short)f2bf(f0.y);
        a[2] = (short)f2bf(f0.z); a[3] = (short)f2bf(f0.w);
        a[4] = (short)f2bf(f1.x); a[5] = (short)f2bf(f1.y);
        a[6] = (short)f2bf(f1.z); a[7] = (short)f2bf(f1.w);
      }
      if (!val2) a = (bf16x8)0;
      R1[d] = a;
    }
  }

  // ---- MFMA sweeps (hi-precision W only) ----
  f32x4 acc0 = {0.f, 0.f, 0.f, 0.f};
  f32x4 acc1 = {0.f, 0.f, 0.f, 0.f};
  const uint4* bfp = (const uint4*)Bf;
#pragma unroll
  for (int d = 0; d < 7; ++d) {
    if (d < kn) {
      int k = kb + d;
      uint4 h0 = bfp[(k * 2 + 0) * 64 + lane];
      uint4 h1 = bfp[(k * 2 + 1) * 64 + lane];
      acc0 = __builtin_amdgcn_mfma_f32_16x16x32_bf16(
          R0[d], *reinterpret_cast<const bf16x8*>(&h0), acc0, 0, 0, 0);
      acc1 = __builtin_amdgcn_mfma_f32_16x16x32_bf16(
          R0[d], *reinterpret_cast<const bf16x8*>(&h1), acc1, 0, 0, 0);
    }
  }
  if (PACKED) {
#pragma unroll
    for (int d = 0; d < 7; ++d) {
      if (d < kn) {
        int k = kb + d;
        uint4 h0 = bfp[(k * 2 + 0) * 64 + lane];
        uint4 h1 = bfp[(k * 2 + 1) * 64 + lane];
        acc0 = __builtin_amdgcn_mfma_f32_16x16x32_bf16(
            R1[d], *reinterpret_cast<const bf16x8*>(&h0), acc0, 0, 0, 0);
        acc1 = __builtin_amdgcn_mfma_f32_16x16x32_bf16(
            R1[d], *reinterpret_cast<const bf16x8*>(&h1), acc1, 0, 0, 0);
      }
    }
  }

  // ---- dump partials (C/D: col=lane&15, row=quad*4+reg — m89/m91) ----
#pragma unroll
  for (int reg = 0; reg < 4; ++reg) {
    int row = quad * 4 + reg;
    plane[w][row][r16] = acc0[reg];
    plane[w][row][16 + r16] = acc1[reg];
  }

  // ---- residual overflow: entries i = w, w+4, ... ; dist-1 prefetch ----
  const int c32 = lane & 31, h = lane >> 5;
  int i = w;
  int e_cur = 0;
  float4 p0, p1, p2, p3;
  if (i < tot) {
    e_cur = flatE[i];
    const float4* ar =
        (const float4*)(in_feature + ((e_cur & 0x3FFFF) << 5) + (h << 4));
    p0 = ar[0]; p1 = ar[1]; p2 = ar[2]; p3 = ar[3];
  }
  while (i < tot) {
    const int e = e_cur;
    float4 q0 = p0, q1 = p1, q2 = p2, q3 = p3;
    const int inext = i + 4;
    if (inext < tot) {
      e_cur = flatE[inext];
      const float4* ar =
          (const float4*)(in_feature + ((e_cur & 0x3FFFF) << 5) + (h << 4));
      p0 = ar[0]; p1 = ar[1]; p2 = ar[2]; p3 = ar[3];
    }
    const int k2 = (e >> LOG2_NV) & 31;
    const int rr = (e >> 24) & 15;
    const float* wcol = kernel_w + (k2 << 10) + (h << 4) * C_CH + c32;
    float psum = 0.f;
    psum = fmaf(q0.x, wcol[0 * C_CH], psum);
    psum = fmaf(q0.y, wcol[1 * C_CH], psum);
    psum = fmaf(q0.z, wcol[2 * C_CH], psum);
    psum = fmaf(q0.w, wcol[3 * C_CH], psum);
    psum = fmaf(q1.x, wcol[4 * C_CH], psum);
    psum = fmaf(q1.y, wcol[5 * C_CH], psum);
    psum = fmaf(q1.z, wcol[6 * C_CH], psum);
    psum = fmaf(q1.w, wcol[7 * C_CH], psum);
    psum = fmaf(q2.x, wcol[8 * C_CH], psum);
    psum = fmaf(q2.y, wcol[9 * C_CH], psum);
    psum = fmaf(q2.z, wcol[10 * C_CH], psum);
    psum = fmaf(q2.w, wcol[11 * C_CH], psum);
    psum = fmaf(q3.x, wcol[12 * C_CH], psum);
    psum = fmaf(q3.y, wcol[13 * C_CH], psum);
    psum = fmaf(q3.z, wcol[14 * C_CH], psum);
    psum = fmaf(q3.w, wcol[15 * C_CH], psum);
    psum += __shfl_xor(psum, 32);
    if (h == 0) plane[w][rr][c32] += psum;    // own plane: no cross-wave race
    i = inext;
  }

  // ---- merge 4 planes + bias, one float2 store per thread ----
  __syncthreads();
  const int mr = tid >> 4;
  const int mc = (tid & 15) << 1;
  float s0 = plane[0][mr][mc] + plane[1][mr][mc] + plane[2][mr][mc] +
             plane[3][mr][mc] + bias[mc];
  float s1 = plane[0][mr][mc + 1] + plane[1][mr][mc + 1] +
             plane[2][mr][mc + 1] + plane[3][mr][mc + 1] + bias[mc + 1];
  float2 o; o.x = s0; o.y = s1;
  *(float2*)(out + ((vb + mr) << 5) + mc) = o;
}

// ---------------------------------------------------------------------------
// Emergency finisher: the ~tens of entries that overflowed S2.
__global__ __launch_bounds__(BLOCK) void emergency_kernel(
    const float* __restrict__ in_feature, const float* __restrict__ kernel_w,
    const int* __restrict__ ecnt, const int2* __restrict__ elist,
    float* __restrict__ out) {
  int e = blockIdx.x * BLOCK + threadIdx.x;
  int n = *ecnt;
  if (n > ECAP) n = ECAP;
  if (e >= n) return;
  int2 ent = elist[e];
  int v = ent.x, k = ent.y >> LOG2_NV, in = ent.y & 0x3FFFF;
  float a[C_CH];
  const float4* ar = (const float4*)(in_feature + (in << 5));
#pragma unroll
  for (int q = 0; q < 8; ++q) ((float4*)a)[q] = ar[q];
  for (int c = 0; c < C_CH; ++c) {
    float s = 0.f;
#pragma unroll
    for (int i = 0; i < C_CH; ++i)
      s = fmaf(a[i], kernel_w[(k << 10) + i * C_CH + c], s);
    atomicAdd(&out[v * C_CH + c], s);
  }
}

// ---------------------------------------------------------------------------
// Fallback (tiny ws): round-1 direct-atomic version. Correct, slow.
__global__ __launch_bounds__(BLOCK) void init_bias_kernel(
    float* __restrict__ out, const float* __restrict__ bias, int n4) {
  int idx = blockIdx.x * blockDim.x + threadIdx.x;
  if (idx >= n4) return;
  ((float4*)out)[idx] = ((const float4*)bias)[idx & 7];
}

__global__ __launch_bounds__(BLOCK) void scatter_conv_kernel(
    const float* __restrict__ in_feature, const float* __restrict__ kernel_w,
    const int* __restrict__ nbmap, float* __restrict__ out) {
  const int k = blockIdx.x >> 9;
  const int pair = blockIdx.x * BLOCK + threadIdx.x;
  const float* __restrict__ Wk = kernel_w + k * (C_CH * C_CH);
  const int2 nb = ((const int2*)nbmap)[pair];
  const float4* __restrict__ inrow =
      (const float4*)(in_feature + (long)nb.x * C_CH);
  float a[C_CH];
#pragma unroll
  for (int j = 0; j < 8; ++j) ((float4*)a)[j] = inrow[j];
  float acc[C_CH];
#pragma unroll
  for (int c = 0; c < C_CH; ++c) acc[c] = 0.0f;
#pragma unroll
  for (int i = 0; i < C_CH; ++i) {
    const float av = a[i];
#pragma unroll
    for (int c = 0; c < C_CH; ++c)
      acc[c] = fmaf(av, Wk[i * C_CH + c], acc[c]);
  }
  float* __restrict__ orow = out + (long)nb.y * C_CH;
#pragma unroll
  for (int c = 0; c < C_CH; ++c) atomicAdd(orow + c, acc[c]);
}

// ===========================================================================
extern "C" void kernel_launch(void* const* d_in, const int* in_sizes, int n_in,
                              void* d_out, int out_size, void* d_ws,
                              size_t ws_size, hipStream_t stream) {
  const float* in_feature = (const float*)d_in[0];
  const float* kernel_w   = (const float*)d_in[1];
  const float* bias       = (const float*)d_in[2];
  const int*   nbmap      = (const int*)d_in[3];
  float* out = (float*)d_out;
  const int M = in_sizes[3] / 2;                 // 3,538,944
  const int Mq = M / 4;                          // quads of pairs (exact)

  // ws (ints): T64[54N] (packed) or T[27N] (legacy) | ovf_cnt[N] | ecnt[64]
  //            | elist[2*ECAP] | Bf[13824] | ovf[S2*N] | feat16[16N if use16]
  const long FIXED = 64 + 2 * ECAP + 13824;
  long ws_ints = (long)(ws_size / 4);
  long planes = (ws_ints - FIXED) / N_VOX;       // 1 MB planes
  int packed = 0, use16 = 0;
  long s2c;
  if (planes >= 75) {                            // tier 0: T64+feat16+S2>=4
    packed = 1; use16 = 1;
    s2c = planes - 71;
    if (s2c > 7) s2c = 7;
  } else if (planes >= 59) {                     // tier 1: T64, f32 rows
    packed = 1;
    s2c = planes - 55;
    if (s2c > 7) s2c = 7;
  } else {                                       // tier 2: legacy single T
    s2c = planes - 28;
    if (s2c > 15) s2c = 15;
  }
  int S2 = (int)s2c;

  if (!packed && S2 < 4) {                       // tier 3: direct atomics
    const int n4 = out_size / 4;
    init_bias_kernel<<<(n4 + BLOCK - 1) / BLOCK, BLOCK, 0, stream>>>(out, bias,
                                                                     n4);
    scatter_conv_kernel<<<M / BLOCK, BLOCK, 0, stream>>>(in_feature, kernel_w,
                                                         nbmap, out);
    return;
  }

  const long planesT = packed ? 2L * K3 : (long)K3;   // in 1MB int-planes
  int* Tbase    = (int*)d_ws;                       // T64 or T
  int* ovf_cnt  = Tbase + planesT * N_VOX;          // [N_VOX]
  int* ecnt     = ovf_cnt + N_VOX;                  // [64] (use [0])
  int2* elist   = (int2*)(ecnt + 64);               // [ECAP]
  unsigned short* Bf = (unsigned short*)(ecnt + 64 + 2 * ECAP);  // [27648]
  int* ovf      = ((int*)Bf) + 13824;               // [S2][N_VOX]
  unsigned short* feat16 = (unsigned short*)(ovf + (long)S2 * N_VOX);

  // Single setup kernel: clears + Bf (+feat16).
  const long nt4 = planesT * N_VOX / 4;             // int4 units
  const long nc4 = (N_VOX + 64) / 4;
  const long total = nt4 + nc4 + (use16 ? (long)NF16 : 0) + FRAGN;
  const long sblocks = (total + BLOCK - 1) / BLOCK;
  setup_kernel<<<(int)sblocks, BLOCK, 0, stream>>>(
      (int4*)Tbase, nt4, (int4*)ovf_cnt, nc4, in_feature, feat16, use16,
      kernel_w, Bf);

  if (packed) {
    passA_packed<<<(Mq + BLOCK - 1) / BLOCK, BLOCK, 0, stream>>>(
        (const int4*)nbmap, (ull*)Tbase, Mq);
    passB_packed<<<(Mq + BLOCK - 1) / BLOCK, BLOCK, 0, stream>>>(
        (const int4*)nbmap, (ull*)Tbase, ovf_cnt, ovf, S2, ecnt, elist, Mq);
    if (use16)
      gather_splitk_kernel<1, 1><<<N_VOX / 16, BLOCK, 0, stream>>>(
          in_feature, feat16, kernel_w, bias, (const void*)Tbase, ovf_cnt,
          ovf, Bf, out, S2);
    else
      gather_splitk_kernel<1, 0><<<N_VOX / 16, BLOCK, 0, stream>>>(
          in_feature, feat16, kernel_w, bias, (const void*)Tbase, ovf_cnt,
          ovf, Bf, out, S2);
  } else {
    passA_legacy<<<(M + BLOCK - 1) / BLOCK, BLOCK, 0, stream>>>(
        (const int2*)nbmap, Tbase, M);
    passB_legacy<<<(M + BLOCK - 1) / BLOCK, BLOCK, 0, stream>>>(
        (const int2*)nbmap, Tbase, ovf_cnt, ovf, S2, ecnt, elist, M);
    gather_splitk_kernel<0, 0><<<N_VOX / 16, BLOCK, 0, stream>>>(
        in_feature, feat16, kernel_w, bias, (const void*)Tbase, ovf_cnt, ovf,
        Bf, out, S2);
  }
  emergency_kernel<<<ECAP / BLOCK, BLOCK, 0, stream>>>(in_feature, kernel_w,
                                                       ecnt, elist, out);
}